// Round 4
// baseline (3304.199 us; speedup 1.0000x reference)
//
#include <hip/hip_runtime.h>
#include <hip/hip_bf16.h>

typedef __attribute__((ext_vector_type(8))) short bf16x8;
typedef __attribute__((ext_vector_type(4))) float f32x4;
typedef __attribute__((ext_vector_type(2))) float f32x2;

#define NB 64
#define NT 512
#define ND 512
#define NU 512

__device__ __forceinline__ unsigned short f2bf(float f) {
  union { float f; unsigned int u; } v; v.f = f;
  unsigned int r = v.u + 0x7fffu + ((v.u >> 16) & 1u);
  return (unsigned short)(r >> 16);
}
__device__ __forceinline__ float bf2f(unsigned short h) {
  union { unsigned int u; float f; } v; v.u = ((unsigned int)h) << 16;
  return v.f;
}
__device__ __forceinline__ float sigm(float x) {
  return 1.f / (1.f + __expf(-x));
}
__device__ __forceinline__ float tanh_f(float x) {
  float ax = fminf(fabsf(x), 15.f);
  float e = __expf(2.f * ax);
  float t = (e - 1.f) / (e + 1.f);
  return copysignf(t, x);
}

// ---------------- prep kernels ----------------

__global__ void k_cvt_x(const float* __restrict__ X, unsigned short* __restrict__ Xb, int n) {
  int i = (blockIdx.x * 256 + threadIdx.x) * 4;
  if (i < n) {
    float4 v = *(const float4*)(X + i);
    ushort4 o;
    o.x = f2bf(v.x); o.y = f2bf(v.y); o.z = f2bf(v.z); o.w = f2bf(v.w);
    *(ushort4*)(Xb + i) = o;
  }
}

// WxcatT [c=2048][k=512] bf16, c = u*4 + gate, from x-part rows (512..1023) of W
__global__ void k_wx(const float* __restrict__ Wf, const float* __restrict__ Wi,
                     const float* __restrict__ Wc, const float* __restrict__ Wo,
                     unsigned short* __restrict__ Wt) {
  int idx = blockIdx.x * 256 + threadIdx.x;   // 2048*512 threads
  int c = idx >> 9, k = idx & 511;
  int gate = c & 3, u = c >> 2;
  const float* W = (gate == 0) ? Wf : (gate == 1) ? Wi : (gate == 2) ? Wc : Wo;
  Wt[idx] = f2bf(W[(512 + k) * 512 + u]);
}

// WhPack: per block j, B-frag order: chunk = ((j*16+ks)*2+cg)*64+lane, 8 bf16 per chunk.
// Unit map: col n=cl&15 -> unit = j*8 + 2*(n>>2) + cgi  (adjacent-unit pairs per thread)
__global__ void k_whpack(const float* __restrict__ Wf, const float* __restrict__ Wi,
                         const float* __restrict__ Wc, const float* __restrict__ Wo,
                         unsigned short* __restrict__ P) {
  int chunk = blockIdx.x * 256 + threadIdx.x;   // 131072
  int lane = chunk & 63;
  int cgi = (chunk >> 6) & 1;
  int ks = (chunk >> 7) & 15;
  int j = chunk >> 11;
  int cl = cgi * 16 + (lane & 15);
  int u = j * 8 + ((((cl & 15) >> 2)) << 1) + (cl >> 4);
  int gate = cl & 3;
  const float* W = (gate == 0) ? Wf : (gate == 1) ? Wi : (gate == 2) ? Wc : Wo;
  int kb = ks * 32 + (lane >> 4) * 8;
  ushort4 lo, hi;
  lo.x = f2bf(W[(kb + 0) * 512 + u]); lo.y = f2bf(W[(kb + 1) * 512 + u]);
  lo.z = f2bf(W[(kb + 2) * 512 + u]); lo.w = f2bf(W[(kb + 3) * 512 + u]);
  hi.x = f2bf(W[(kb + 4) * 512 + u]); hi.y = f2bf(W[(kb + 5) * 512 + u]);
  hi.z = f2bf(W[(kb + 6) * 512 + u]); hi.w = f2bf(W[(kb + 7) * 512 + u]);
  *(ushort4*)(P + chunk * 8) = lo;
  *(ushort4*)(P + chunk * 8 + 4) = hi;
}

// ---------------- phase A: xproj = Xb @ WxcatT^T, output bf16 [32768][2048] ----------------

#define LDAP 72   // padded row stride (elems) to break bank conflicts

__global__ void __launch_bounds__(256)
k_gemm_xproj(const unsigned short* __restrict__ Xb,
             const unsigned short* __restrict__ Wt,
             unsigned short* __restrict__ xproj) {
  __shared__ unsigned short As[128 * LDAP];
  __shared__ unsigned short Bs[128 * LDAP];
  const int tid = threadIdx.x;
  const int bid = blockIdx.x;
  const int mt = bid >> 4;
  const int ntile = bid & 15;
  const int m0 = mt * 128, n0 = ntile * 128;
  const int lane = tid & 63, w = tid >> 6;
  const int wm = w >> 1, wn = w & 1;

  const unsigned short* aSrc = Xb + (long)(m0 + (tid >> 3)) * 512 + (tid & 7) * 8;
  const unsigned short* bSrc = Wt + (long)(n0 + (tid >> 3)) * 512 + (tid & 7) * 8;
  const int ldsRow = (tid >> 3);          // +c*32 per chunk
  const int ldsK = (tid & 7) * 8;

  f32x4 acc[4][4] = {};
  bf16x8 sa[4], sb[4];

#pragma unroll
  for (int c = 0; c < 4; c++) {
    sa[c] = *(const bf16x8*)(aSrc + (long)c * 32 * 512);
    sb[c] = *(const bf16x8*)(bSrc + (long)c * 32 * 512);
  }
  for (int kk = 0; kk < 8; kk++) {
    __syncthreads();
#pragma unroll
    for (int c = 0; c < 4; c++) {
      *(bf16x8*)(As + (c * 32 + ldsRow) * LDAP + ldsK) = sa[c];
      *(bf16x8*)(Bs + (c * 32 + ldsRow) * LDAP + ldsK) = sb[c];
    }
    __syncthreads();
    if (kk < 7) {
      const unsigned short* aS = aSrc + (kk + 1) * 64;
      const unsigned short* bS = bSrc + (kk + 1) * 64;
#pragma unroll
      for (int c = 0; c < 4; c++) {
        sa[c] = *(const bf16x8*)(aS + (long)c * 32 * 512);
        sb[c] = *(const bf16x8*)(bS + (long)c * 32 * 512);
      }
    }
#pragma unroll
    for (int ks = 0; ks < 2; ks++) {
      bf16x8 afr[4], bfr[4];
#pragma unroll
      for (int i = 0; i < 4; i++)
        afr[i] = *(const bf16x8*)(As + (wm * 64 + i * 16 + (lane & 15)) * LDAP + ks * 32 + (lane >> 4) * 8);
#pragma unroll
      for (int i = 0; i < 4; i++)
        bfr[i] = *(const bf16x8*)(Bs + (wn * 64 + i * 16 + (lane & 15)) * LDAP + ks * 32 + (lane >> 4) * 8);
#pragma unroll
      for (int i = 0; i < 4; i++)
#pragma unroll
        for (int jn = 0; jn < 4; jn++)
          acc[i][jn] = __builtin_amdgcn_mfma_f32_16x16x32_bf16(afr[i], bfr[jn], acc[i][jn], 0, 0, 0);
    }
  }
#pragma unroll
  for (int i = 0; i < 4; i++) {
    int row = m0 + wm * 64 + i * 16 + (lane >> 4) * 4;
#pragma unroll
    for (int jn = 0; jn < 4; jn++) {
      int col = n0 + wn * 64 + jn * 16 + (lane & 15);
#pragma unroll
      for (int r = 0; r < 4; r++)
        xproj[(long)(row + r) * 2048 + col] = f2bf(acc[i][jn][r]);
    }
  }
}

// ---------------- phase B: recurrence, 64 blocks x 256 threads ----------------
// No __syncthreads, no fences, no L2 invalidates in the loop. All sync traffic
// (h data, flags) moves through the coherence point via sc1 stores/loads:
//  producer: one packed 4B sc1 store per thread -> vmcnt drain -> per-wave flag.
//  consumer: poll 64 flags (4B stride), then inline-asm sc1 dwordx4 h loads.

__device__ __forceinline__ float4 quad_transpose(f32x4 v, int g) {
  // v[r] = M[r][g] within a 4-lane quad; returns y[c] = M[g][c].
  const bool odd = g & 1;
  float s0 = odd ? v[0] : v[1];
  float s1 = odd ? v[2] : v[3];
  float r0 = __shfl_xor(s0, 1, 64);
  float r1 = __shfl_xor(s1, 1, 64);
  float X0 = odd ? r0 : v[0];
  float X1 = odd ? v[1] : r0;
  float X2 = odd ? r1 : v[2];
  float X3 = odd ? v[3] : r1;
  const bool hi = g & 2;
  float t0 = hi ? X0 : X2;
  float t1 = hi ? X1 : X3;
  float q0 = __shfl_xor(t0, 2, 64);
  float q1 = __shfl_xor(t1, 2, 64);
  float4 y;
  y.x = hi ? q0 : X0;
  y.y = hi ? q1 : X1;
  y.z = hi ? X2 : q0;
  y.w = hi ? X3 : q1;
  return y;
}

__global__ void __launch_bounds__(256)
k_lstm(const unsigned short* __restrict__ xproj,
       const unsigned short* __restrict__ WhP,
       unsigned short* __restrict__ Hp,
       unsigned int* __restrict__ flags,
       const float* __restrict__ Bf, const float* __restrict__ Bi,
       const float* __restrict__ Bc, const float* __restrict__ Bo,
       float* __restrict__ out) {
  const int j = blockIdx.x;
  const int tid = threadIdx.x;
  const int lane = tid & 63;
  const int w = tid >> 6;

  // persistent weight B-frags in registers: 32 frags = 128 regs
  bf16x8 bfrag[16][2];
#pragma unroll
  for (int ks = 0; ks < 16; ks++)
#pragma unroll
    for (int cgi = 0; cgi < 2; cgi++)
      bfrag[ks][cgi] = *(const bf16x8*)(WhP + ((((j * 16 + ks) * 2 + cgi) * 64 + lane) << 3));

  // thread's (batch, unit) ownership after the quad transpose
  const int g = lane & 3;
  const int up = (lane & 15) >> 2;                  // u' in [0,4)
  const int b = w * 16 + ((lane >> 4) << 2) + g;    // batch
  const int U0 = j * 8 + 2 * up;                    // acc0 -> U0, acc1 -> U0+1

  float c0 = 0.f, c1 = 0.f;
  const float bF0 = Bf[U0], bI0 = Bi[U0], bC0 = Bc[U0], bO0 = Bo[U0];
  const float bF1 = Bf[U0 + 1], bI1 = Bi[U0 + 1], bC1 = Bc[U0 + 1], bO1 = Bo[U0 + 1];

  // xproj: gates for units U0,U0+1 are 8 consecutive bf16 -> one 16B load
  const unsigned short* xp0 = xproj + (long)b * NT * 2048 + j * 32 + up * 8;
  float* out0 = out + (long)b * NT * NU + U0;

  // h store chunk (A-frag layout): ((j>>2)*4 + w)*64 + (b&15) + ((j&3)<<4); elems 2up,2up+1
  const int chunk = ((j >> 2) * 4 + w) * 64 + (b & 15) + ((j & 3) << 4);
  unsigned int* hdst32 = (unsigned int*)Hp + (chunk << 2) + up;

  unsigned int* pubflag = flags + w * 64 + j;
  const unsigned int* pollbase = flags + w * 64 + lane;  // lane l -> block l, plane w

  for (int t = 0; t < NT; t++) {
    // xproj load is independent of h_t: issue before the poll to overlap the wait
    uint4 xv = *(const uint4*)(xp0 + (long)t * 2048);

    if (t > 0) {
      while (!__all(__hip_atomic_load(pollbase, __ATOMIC_RELAXED,
                                      __HIP_MEMORY_SCOPE_AGENT) >= (unsigned)t)) {
      }
    }
    __builtin_amdgcn_sched_barrier(0);

    // h A-frags: sc1 loads straight from the coherence point (no L2 invalidate needed)
    const unsigned short* hp = Hp + (t & 1) * 32768;
    bf16x8 af[16];
#pragma unroll
    for (int ks = 0; ks < 16; ks++) {
      asm volatile("global_load_dwordx4 %0, %1, off sc1"
                   : "=v"(af[ks])
                   : "v"(hp + (((ks * 4 + w) * 64 + lane) << 3)));
    }
    asm volatile("s_waitcnt vmcnt(0)" ::: "memory");
    __builtin_amdgcn_sched_barrier(0);

    // 4 independent 8-deep MFMA chains
    f32x4 a0 = {0.f, 0.f, 0.f, 0.f}, a0b = {0.f, 0.f, 0.f, 0.f};
    f32x4 a1 = {0.f, 0.f, 0.f, 0.f}, a1b = {0.f, 0.f, 0.f, 0.f};
#pragma unroll
    for (int ks = 0; ks < 8; ks++) {
      a0 = __builtin_amdgcn_mfma_f32_16x16x32_bf16(af[ks], bfrag[ks][0], a0, 0, 0, 0);
      a1 = __builtin_amdgcn_mfma_f32_16x16x32_bf16(af[ks], bfrag[ks][1], a1, 0, 0, 0);
      a0b = __builtin_amdgcn_mfma_f32_16x16x32_bf16(af[ks + 8], bfrag[ks + 8][0], a0b, 0, 0, 0);
      a1b = __builtin_amdgcn_mfma_f32_16x16x32_bf16(af[ks + 8], bfrag[ks + 8][1], a1b, 0, 0, 0);
    }
    f32x4 acc0 = a0 + a0b;
    f32x4 acc1 = a1 + a1b;

    // in-register gate exchange: 4x4 transpose within each quad
    float4 G0 = quad_transpose(acc0, g);
    float4 G1 = quad_transpose(acc1, g);

    float f0 = sigm(G0.x + bf2f((unsigned short)(xv.x & 0xffff)) + bF0);
    float i0 = sigm(G0.y + bf2f((unsigned short)(xv.x >> 16)) + bI0);
    float g0 = tanh_f(G0.z + bf2f((unsigned short)(xv.y & 0xffff)) + bC0);
    float o0 = sigm(G0.w + bf2f((unsigned short)(xv.y >> 16)) + bO0);
    c0 = f0 * c0 + i0 * g0;
    float h0 = o0 * tanh_f(c0);
    float f1 = sigm(G1.x + bf2f((unsigned short)(xv.z & 0xffff)) + bF1);
    float i1 = sigm(G1.y + bf2f((unsigned short)(xv.z >> 16)) + bI1);
    float g1 = tanh_f(G1.z + bf2f((unsigned short)(xv.w & 0xffff)) + bC1);
    float o1 = sigm(G1.w + bf2f((unsigned short)(xv.w >> 16)) + bO1);
    c1 = f1 * c1 + i1 * g1;
    float h1 = o1 * tanh_f(c1);

    // publish h: ONE packed 4B sc1 store per thread (one instruction per wave)
    unsigned int hw = (unsigned int)f2bf(h0) | ((unsigned int)f2bf(h1) << 16);
    __hip_atomic_store(hdst32 + (((t + 1) & 1) << 14), hw, __ATOMIC_RELAXED,
                       __HIP_MEMORY_SCOPE_AGENT);
    asm volatile("s_waitcnt vmcnt(0)" ::: "memory");   // h acked at coherence point
    if (lane == 0)
      __hip_atomic_store(pubflag, (unsigned)(t + 1), __ATOMIC_RELAXED,
                         __HIP_MEMORY_SCOPE_AGENT);
    asm volatile("" ::: "memory");                     // keep out stores below the flag

    // out stores AFTER the release, nontemporal (no write-allocate)
    f32x2 o2 = {h0, h1};
    __builtin_nontemporal_store(o2, (f32x2*)(out0 + (long)t * NU));
  }
}

// ---------------- host ----------------

extern "C" void kernel_launch(void* const* d_in, const int* in_sizes, int n_in,
                              void* d_out, int out_size, void* d_ws, size_t ws_size,
                              hipStream_t stream) {
  const float* X  = (const float*)d_in[0];
  const float* Wf = (const float*)d_in[1];
  const float* Bf = (const float*)d_in[2];
  const float* Wi = (const float*)d_in[3];
  const float* Bi = (const float*)d_in[4];
  const float* Wc = (const float*)d_in[5];
  const float* Bc = (const float*)d_in[6];
  const float* Wo = (const float*)d_in[7];
  const float* Bo = (const float*)d_in[8];
  float* out = (float*)d_out;

  // workspace layout (bytes). Hp+flags live in the Xb region (dead after the
  // x-projection GEMM); their memset is stream-ordered after k_gemm_xproj.
  const size_t XB_OFF  = 0;                       // 33,554,432 (Xb; later Hp+flags)
  const size_t HP_OFF  = 0;                       // 131,072   (2x 64KB ping-pong)
  const size_t FL_OFF  = 131072;                  // 1,024     (256 flags, 4B stride)
  const size_t WT_OFF  = 33554432;                // 2,097,152
  const size_t XP_OFF  = 35651584;                // 134,217,728
  const size_t WHP_OFF = 169869312;               // 2,097,152
  const size_t NEEDED  = 171966464;
  if (ws_size < NEEDED) return;

  char* ws = (char*)d_ws;
  unsigned short* Xb    = (unsigned short*)(ws + XB_OFF);
  unsigned short* Wt    = (unsigned short*)(ws + WT_OFF);
  unsigned short* xproj = (unsigned short*)(ws + XP_OFF);
  unsigned short* WhP   = (unsigned short*)(ws + WHP_OFF);
  unsigned short* Hp    = (unsigned short*)(ws + HP_OFF);
  unsigned int*   flags = (unsigned int*)(ws + FL_OFF);

  k_cvt_x<<<16384, 256, 0, stream>>>(X, Xb, NB * NT * ND);
  k_wx<<<4096, 256, 0, stream>>>(Wf, Wi, Wc, Wo, Wt);
  k_whpack<<<512, 256, 0, stream>>>(Wf, Wi, Wc, Wo, WhP);
  k_gemm_xproj<<<4096, 256, 0, stream>>>(Xb, Wt, xproj);
  hipMemsetAsync(ws + HP_OFF, 0, 131072 + 1024, stream);  // after GEMM: Xb is dead

  const unsigned short* xp_a = xproj;
  const unsigned short* whp_a = WhP;
  unsigned short* hp_a = Hp;
  unsigned int* fl_a = flags;
  const float *bf_a = Bf, *bi_a = Bi, *bc_a = Bc, *bo_a = Bo;
  float* out_a = out;
  void* args[9] = {&xp_a, &whp_a, &hp_a, &fl_a, &bf_a, &bi_a, &bc_a, &bo_a, &out_a};
  hipLaunchCooperativeKernel((void*)k_lstm, dim3(64), dim3(256), args, 0, stream);
}